// Round 4
// baseline (35.687 us; speedup 1.0000x reference)
//
#include <hip/hip_runtime.h>

#define NJ 22
#define CAM_DIM 3
#define RSTRIDE 224   // per-i: 198 floats R + 22 floats n2 + 4 pad

// Kernel 1: one thread per (prediction, joint) -> R fragment, ||R||^2, gate key.
__global__ void precompute_kernel(const float* __restrict__ params,
                                  const int* __restrict__ batch_ids,
                                  const int* __restrict__ czyx,
                                  float* __restrict__ ws_R,
                                  int* __restrict__ ws_key,
                                  int n, int param_dim) {
    int t = blockIdx.x * blockDim.x + threadIdx.x;
    if (t >= n * NJ) return;
    int i = t / NJ;
    int k = t - i * NJ;

    if (k == 0) {
        ws_key[i] = (batch_ids[i] << 16) | (czyx[i*3+1] << 8) | czyx[i*3+2];
    }

    const float* p = params + (size_t)i * param_dim + CAM_DIM + k * 6;
    float a1x = p[0], a2x = p[1];
    float a1y = p[2], a2y = p[3];
    float a1z = p[4], a2z = p[5];

    float n1 = sqrtf(a1x*a1x + a1y*a1y + a1z*a1z);
    float b1x = a1x / n1, b1y = a1y / n1, b1z = a1z / n1;

    float d = b1x*a2x + b1y*a2y + b1z*a2z;
    float px = a2x - d*b1x, py = a2y - d*b1y, pz = a2z - d*b1z;
    float np = sqrtf(px*px + py*py + pz*pz);
    float b2x = px / np, b2y = py / np, b2z = pz / np;

    float b3x = b1y*b2z - b1z*b2y;
    float b3y = b1z*b2x - b1x*b2z;
    float b3z = b1x*b2y - b1y*b2x;

    float r[9] = {b1x,b1y,b1z,b2x,b2y,b2z,b3x,b3y,b3z};
    float* Ri = ws_R + (size_t)i * RSTRIDE;
    float s = 0.0f;
    #pragma unroll
    for (int a = 0; a < 9; ++a) {
        Ri[k*9 + a] = r[a];
        s += r[a] * r[a];
    }
    Ri[198 + k] = s;   // same accumulation order as the pair dot -> exact 0 diagonal
}

// Kernel 2: one block per row. Gate all j's via bitmask (cheap, unrolled);
// pose path exists ONCE, entered via ffs-walk only on hit lanes (~2 per row).
// Dense row store (two float4/thread). Row argmax in an LDS u64 slot -> nms.
__global__ __launch_bounds__(256) void fused_score_kernel(
        const float* __restrict__ ts,
        const float* __restrict__ ws_R,
        const int* __restrict__ ws_key,
        float* __restrict__ out,
        float* __restrict__ nms,
        int n) {
    __shared__ unsigned long long slot;

    const int i   = blockIdx.x;
    const int tid = threadIdx.x;

    if (tid == 0) slot = 0x00000000FFFFFFFFull;  // (score=0.0f, ~j with j=0)
    __syncthreads();

    const int key_i = ws_key[i];
    const int bi  = key_i >> 16;
    const int ciy = (key_i >> 8) & 0xff;
    const int cix = key_i & 0xff;
    const float* Ri = ws_R + (size_t)i * RSTRIDE;
    float* row = out + (size_t)i * n;

    for (int j0 = tid * 8; j0 < n; j0 += blockDim.x * 8) {
        int kj[8];
        if (j0 + 7 < n) {
            int4 ka = *reinterpret_cast<const int4*>(ws_key + j0);
            int4 kb = *reinterpret_cast<const int4*>(ws_key + j0 + 4);
            kj[0]=ka.x; kj[1]=ka.y; kj[2]=ka.z; kj[3]=ka.w;
            kj[4]=kb.x; kj[5]=kb.y; kj[6]=kb.z; kj[7]=kb.w;
        } else {
            for (int u = 0; u < 8; ++u)
                kj[u] = (j0 + u < n) ? ws_key[j0 + u] : ~key_i;  // ~key_i: batch mismatch
        }

        // gate bits (compile-time indexing only)
        int okmask = 0;
        #pragma unroll
        for (int u = 0; u < 8; ++u) {
            int key_j = kj[u];
            int dy = ((key_j >> 8) & 0xff) - ciy;
            int dx = (key_j & 0xff) - cix;
            if (((key_j >> 16) == bi) && (dy*dy + dx*dx <= 25))
                okmask |= 1 << u;
        }

        // single pose-path copy, walked over set bits (rare)
        int passmask = 0;
        while (okmask) {
            int u = __ffs(okmask) - 1;
            okmask &= okmask - 1;
            int j = j0 + u;
            const float* Rj = ws_R + (size_t)j * RSTRIDE;
            float sum = 0.0f;
            #pragma unroll
            for (int k = 0; k < NJ; ++k) {
                float g = 0.0f;
                #pragma unroll
                for (int a = 0; a < 9; ++a)
                    g += Ri[k*9 + a] * Rj[k*9 + a];
                float d2 = Ri[198 + k] + Rj[198 + k] - 2.0f * g;
                d2 = fmaxf(d2, 0.0f);
                sum += sqrtf(d2);
            }
            float pd = sum / 22.0f;
            if (pd < 2.5f) {
                passmask |= 1 << u;
                float s = ts[j];
                unsigned long long packed =
                    ((unsigned long long)__float_as_uint(s) << 32) |
                    (unsigned int)(~(unsigned int)j);
                atomicMax(&slot, packed);
            }
        }

        // dense store (compile-time indexing; ts reload only on rare pass bits)
        float sc[8];
        #pragma unroll
        for (int u = 0; u < 8; ++u)
            sc[u] = ((passmask >> u) & 1) ? ts[j0 + u] : 0.0f;

        if (j0 + 7 < n) {
            *reinterpret_cast<float4*>(row + j0)     = make_float4(sc[0],sc[1],sc[2],sc[3]);
            *reinterpret_cast<float4*>(row + j0 + 4) = make_float4(sc[4],sc[5],sc[6],sc[7]);
        } else {
            for (int u = 0; u < 8 && j0 + u < n; ++u) row[j0 + u] = sc[u];
        }
    }

    __syncthreads();
    if (tid == 0) {
        unsigned int jwin = ~(unsigned int)(slot & 0xFFFFFFFFull);
        nms[i] = (jwin == (unsigned int)i) ? 1.0f : 0.0f;
    }
}

extern "C" void kernel_launch(void* const* d_in, const int* in_sizes, int n_in,
                              void* d_out, int out_size, void* d_ws, size_t ws_size,
                              hipStream_t stream) {
    const float* params = (const float*)d_in[0];
    const int*   batch  = (const int*)d_in[1];
    const int*   czyx   = (const int*)d_in[2];
    const float* ts     = (const float*)d_in[3];

    const int n = in_sizes[1];                 // N = 2048
    const int param_dim = in_sizes[0] / n;     // 145

    float* ws_R   = (float*)d_ws;                        // n*RSTRIDE f32
    int*   ws_key = (int*)(ws_R + (size_t)n * RSTRIDE);  // n i32

    float* out = (float*)d_out;        // score_map [n*n]
    float* nms = out + (size_t)n * n;  // nms_inds [n] as 0/1 floats

    precompute_kernel<<<(n * NJ + 255) / 256, 256, 0, stream>>>(
        params, batch, czyx, ws_R, ws_key, n, param_dim);

    fused_score_kernel<<<n, 256, 0, stream>>>(ts, ws_R, ws_key, out, nms, n);
}